// Round 5
// baseline (285.799 us; speedup 1.0000x reference)
//
#include <hip/hip_runtime.h>

// EmotionCaps dynamic routing (fp32 I/O):
// u: [B=64, N=1024, I=64] f32; W: [N=1024, E=8, O=32, I=64] f32
// out: v [B=64, E=8, O=32] f32
//
// Structure (4 dispatches; kernel boundaries are the cross-block sync, plus
// a ticket-counter last-block epilogue inside route-2):
//   k_uhat   : u_hat bf16 (32MB ws) via 16x16x32 bf16 MFMA; zeroes s0/s1/s2/ctr.
//   k_route 0: c=1/8            -> atomicAdd s0
//   k_route 1: v0=squash(s0)    -> logits=uh.v0   -> atomicAdd s1
//   k_route 2: v01=v0+v1        -> logits=uh.v01  -> atomicAdd s2
//              + LAST block (device ticket 2047) reads s2 coherently
//                (atomicAdd(addr,0) RMW -> exact bits) and writes out=squash(s2).
// Session ledger (ultra-reproducible bench, <0.1% noise):
//   134.9 baseline (r0/r4) | 146.4 uh2+clamp (r1) | 141.2 uh2 (r2)
//   144.0 partial-sum routes (r3)  -> all real regressions; baseline is a
//   true local optimum. uh2 lesson: route loads must stay 512B/wave-row
//   contiguous. r3 lesson: consumer-side slice-reduce is latency-poison.
// Dead ends prev session: grid.sync 110us/sync, 64-blk fusion 87us (race),
//   spin threadfence+counter 190us/pass. THIS round's fold has NO spinning:
//   2047 blocks ticket-and-exit, one block runs a ~2us epilogue.
// Logit identity b2 = uh.(v0+v1) verified; absmax stable 0.0039.

#define B_  64
#define N_  1024
#define I_  64
#define E_  8
#define O_  32
#define EO_ 256
#define PAD_ 72

typedef __bf16 bf16x8 __attribute__((ext_vector_type(8)));
typedef __bf16 bf16x4v __attribute__((ext_vector_type(4)));
typedef float  f32x4  __attribute__((ext_vector_type(4)));

__device__ __forceinline__ float bf2f(unsigned int h) {
    unsigned int x = (h & 0xffffu) << 16;
    return __builtin_bit_cast(float, x);
}
__device__ __forceinline__ void cvt_store4(unsigned short* dst, float4 q) {
    bf16x4v v;
    v[0] = (__bf16)q.x; v[1] = (__bf16)q.y; v[2] = (__bf16)q.z; v[3] = (__bf16)q.w;
    *(bf16x4v*)dst = v;
}
__device__ __forceinline__ bf16x8 cvt8(const float* __restrict__ p) {
    float4 q0 = *(const float4*)p;
    float4 q1 = *(const float4*)(p + 4);
    bf16x8 a;
    a[0] = (__bf16)q0.x; a[1] = (__bf16)q0.y; a[2] = (__bf16)q0.z; a[3] = (__bf16)q0.w;
    a[4] = (__bf16)q1.x; a[5] = (__bf16)q1.y; a[6] = (__bf16)q1.z; a[7] = (__bf16)q1.w;
    return a;
}
// squash over the 32-elem o-group; lane l holds s[4l..4l+3] of its e-group
// (8 lanes x 4). shfl 1,2,4 stays inside the 8-lane e-group.
__device__ __forceinline__ float4 squash4(float4 s4) {
    float sq = s4.x * s4.x + s4.y * s4.y + s4.z * s4.z + s4.w * s4.w;
    sq += __shfl_xor(sq, 1);
    sq += __shfl_xor(sq, 2);
    sq += __shfl_xor(sq, 4);
    float nrm = sqrtf(sq);
    float sc = sq / ((1.f + sq) * (nrm + 1e-8f));
    return make_float4(sc * s4.x, sc * s4.y, sc * s4.z, sc * s4.w);
}

// ---------------------------------------------------------------------------
// K1: one block per n. D[64b x 256eo] = u[:,n,:] . W[n]^T via 16x16x32 bf16
// MFMA (fragment layouts verified rounds 3-7). u staged in LDS (A-frags);
// W frags streamed from global; D transposed through the SAME LDS buffer
// (union: 33792 B -> 4 blocks/CU) for coalesced uint2 stores.
// Epilogue uses hardware bf16 casts (RNE), not manual bit-twiddling.
// Blocks 0..2 zero s0/s1/s2; block 3 zeroes the ticket counter.
// ---------------------------------------------------------------------------
__global__ __launch_bounds__(256) void k_uhat(const float* __restrict__ u,
                                              const float* __restrict__ W,
                                              unsigned short* __restrict__ uh,
                                              float* __restrict__ s012,
                                              unsigned* __restrict__ ctr) {
    const int n = blockIdx.x;
    const int t = threadIdx.x;
    const int w = t >> 6, l = t & 63;
    const int m16 = l & 15, g = l >> 4;

    if (n < 3) {
        float* sz = s012 + n * (B_ * EO_);
#pragma unroll
        for (int i = 0; i < 64; ++i) sz[i * 256 + t] = 0.f;
    }
    if (n == 3 && t == 0) *ctr = 0u;

    __shared__ __align__(16) unsigned short sh[B_ * 264];   // 33792 B (union)
    unsigned short* ul = sh;        // phase 1: u tile [B_][PAD_]
    unsigned short* Dt = sh;        // phase 2: D tile [B_][264]

#pragma unroll
    for (int j = 0; j < 4; ++j) {
        int idx = j * 256 + t;
        int b = idx >> 4, c = idx & 15;
        float4 q = *(const float4*)(u + (size_t)b * (N_ * I_) + n * I_ + c * 4);
        cvt_store4(&ul[b * PAD_ + c * 4], q);
    }
    __syncthreads();

    bf16x8 afr[4][2];   // A[m=lane&15][k=(lane>>4)*8+j]
#pragma unroll
    for (int mt = 0; mt < 4; ++mt)
#pragma unroll
        for (int ks = 0; ks < 2; ++ks)
            afr[mt][ks] = *(const bf16x8*)&ul[(mt * 16 + m16) * PAD_ + ks * 32 + g * 8];
    __syncthreads();    // all waves done reading ul; sh now reusable as Dt

    f32x4 acc[4][4];
#pragma unroll
    for (int nt = 0; nt < 4; ++nt)
#pragma unroll
        for (int mt = 0; mt < 4; ++mt)
            acc[nt][mt] = (f32x4){0.f, 0.f, 0.f, 0.f};

    const float* Wn = W + (size_t)n * (EO_ * I_);
#pragma unroll
    for (int nt = 0; nt < 4; ++nt) {
        const int eo = w * 64 + nt * 16 + m16;
        const float* wp = Wn + (size_t)eo * I_ + g * 8;
        bf16x8 b0 = cvt8(wp);
        bf16x8 b1 = cvt8(wp + 32);
#pragma unroll
        for (int mt = 0; mt < 4; ++mt) {
            acc[nt][mt] = __builtin_amdgcn_mfma_f32_16x16x32_bf16(afr[mt][0], b0, acc[nt][mt], 0, 0, 0);
            acc[nt][mt] = __builtin_amdgcn_mfma_f32_16x16x32_bf16(afr[mt][1], b1, acc[nt][mt], 0, 0, 0);
        }
    }

    // D lane map: col=lane&15, row=(lane>>4)*4+reg -> LDS transpose (hw cvt)
#pragma unroll
    for (int nt = 0; nt < 4; ++nt) {
        const int col = w * 64 + nt * 16 + m16;
#pragma unroll
        for (int mt = 0; mt < 4; ++mt)
#pragma unroll
            for (int r = 0; r < 4; ++r) {
                __bf16 hv = (__bf16)acc[nt][mt][r];
                Dt[(mt * 16 + g * 4 + r) * 264 + col] =
                    __builtin_bit_cast(unsigned short, hv);
            }
    }
    __syncthreads();
#pragma unroll
    for (int r = 0; r < 16; ++r) {
        const int row = r * 4 + w;
        uint2 q = *(const uint2*)&Dt[row * 264 + l * 4];
        *(uint2*)(uh + (size_t)row * (N_ * EO_) + (size_t)n * EO_ + l * 4) = q;
    }
}

// ---------------------------------------------------------------------------
// K2: one routing pass. 2048 blocks = (b, chunk of 32 n); wave handles 8 n;
// lane l owns eo = 4l..4l+3 (e = l>>3). Shuffle math verified rounds 2-7:
// dot over o = shfl 1,2,4; softmax over E = shfl 8,16,32.
// it selects the v recomputation (from s0/s1, visible since prior dispatch
// completed) and the target accumulator. One atomicAdd per (b,eo) per block.
// it==2 only: fence -> ticket; block with ticket 2047 (all adds globally
// visible) reads s2 via coherent atomic-RMW and writes out = squash(s2).
// ---------------------------------------------------------------------------
__global__ __launch_bounds__(256) void k_route(const unsigned short* __restrict__ uh,
                                               const float* __restrict__ s0,
                                               const float* __restrict__ s1,
                                               float* __restrict__ tgt,
                                               unsigned* __restrict__ ctr,
                                               float* __restrict__ out,
                                               int it) {
    const int blk = blockIdx.x;
    const int b = blk >> 5, chunk = blk & 31;
    const int t = threadIdx.x, wave = t >> 6, l = t & 63;

    const unsigned short* base = uh + (size_t)b * (N_ * EO_)
                                    + (size_t)(chunk * 32 + wave * 8) * EO_ + 4 * l;
    float x[8][4];
    float c[8];

    if (it == 0) {
#pragma unroll
        for (int nn = 0; nn < 8; ++nn) {
            uint2 p = *(const uint2*)(base + nn * EO_);
            x[nn][0] = bf2f(p.x); x[nn][1] = bf2f(p.x >> 16);
            x[nn][2] = bf2f(p.y); x[nn][3] = bf2f(p.y >> 16);
            c[nn] = 0.125f;
        }
    } else {
        // recompute v (and v0+v1 for it==2) from s-buffers: ~20 VALU, L2-hot
        float4 v4 = squash4(*(const float4*)(s0 + b * EO_ + 4 * l));
        if (it == 2) {
            float4 v1 = squash4(*(const float4*)(s1 + b * EO_ + 4 * l));
            v4.x += v1.x; v4.y += v1.y; v4.z += v1.z; v4.w += v1.w;
        }
        float lg[8];
#pragma unroll
        for (int nn = 0; nn < 8; ++nn) {
            uint2 p = *(const uint2*)(base + nn * EO_);
            x[nn][0] = bf2f(p.x); x[nn][1] = bf2f(p.x >> 16);
            x[nn][2] = bf2f(p.y); x[nn][3] = bf2f(p.y >> 16);
            float pd = x[nn][0] * v4.x + x[nn][1] * v4.y
                     + x[nn][2] * v4.z + x[nn][3] * v4.w;
            pd += __shfl_xor(pd, 1);
            pd += __shfl_xor(pd, 2);
            pd += __shfl_xor(pd, 4);              // logit(n,e) in all 8 e-lanes
            lg[nn] = pd;
        }
        float mx[8];
#pragma unroll
        for (int nn = 0; nn < 8; ++nn) mx[nn] = lg[nn];
#pragma unroll
        for (int nn = 0; nn < 8; ++nn) mx[nn] = fmaxf(mx[nn], __shfl_xor(mx[nn], 8));
#pragma unroll
        for (int nn = 0; nn < 8; ++nn) mx[nn] = fmaxf(mx[nn], __shfl_xor(mx[nn], 16));
#pragma unroll
        for (int nn = 0; nn < 8; ++nn) mx[nn] = fmaxf(mx[nn], __shfl_xor(mx[nn], 32));
        float ex[8], sm[8];
#pragma unroll
        for (int nn = 0; nn < 8; ++nn) { ex[nn] = __expf(lg[nn] - mx[nn]); sm[nn] = ex[nn]; }
#pragma unroll
        for (int nn = 0; nn < 8; ++nn) sm[nn] += __shfl_xor(sm[nn], 8);
#pragma unroll
        for (int nn = 0; nn < 8; ++nn) sm[nn] += __shfl_xor(sm[nn], 16);
#pragma unroll
        for (int nn = 0; nn < 8; ++nn) sm[nn] += __shfl_xor(sm[nn], 32);
#pragma unroll
        for (int nn = 0; nn < 8; ++nn) c[nn] = ex[nn] * __builtin_amdgcn_rcpf(sm[nn]);
    }

    float a0 = 0.f, a1 = 0.f, a2 = 0.f, a3 = 0.f;
#pragma unroll
    for (int nn = 0; nn < 8; ++nn) {
        a0 = fmaf(c[nn], x[nn][0], a0); a1 = fmaf(c[nn], x[nn][1], a1);
        a2 = fmaf(c[nn], x[nn][2], a2); a3 = fmaf(c[nn], x[nn][3], a3);
    }

    __shared__ __align__(16) float red[4][EO_];
    *(float4*)&red[wave][4 * l] = make_float4(a0, a1, a2, a3);
    __syncthreads();
    atomicAdd(&tgt[b * EO_ + t], red[0][t] + red[1][t] + red[2][t] + red[3][t]);

    if (it == 2) {
        // make this block's adds globally visible, then ticket
        __threadfence();
        __syncthreads();
        __shared__ int isLast;
        if (t == 0) {
            unsigned tk = atomicAdd(ctr, 1u);
            isLast = (tk == 2047u);
        }
        __syncthreads();
        if (isLast) {
            // all 2048 blocks' s2 adds are visible (fence-before-ticket).
            // Coherent exact read via atomic RMW (+0.0f); plain loads could
            // hit a stale per-XCD L2 line.
#pragma unroll 4
            for (int bb = 0; bb < B_; ++bb) {
                float sv = atomicAdd(&tgt[bb * EO_ + t], 0.f);
                float sq = sv * sv;
                sq += __shfl_xor(sq, 1);
                sq += __shfl_xor(sq, 2);
                sq += __shfl_xor(sq, 4);
                sq += __shfl_xor(sq, 8);
                sq += __shfl_xor(sq, 16);
                float nrm = sqrtf(sq);
                out[bb * EO_ + t] = sq / ((1.f + sq) * (nrm + 1e-8f)) * sv;
            }
        }
    }
}

extern "C" void kernel_launch(void* const* d_in, const int* in_sizes, int n_in,
                              void* d_out, int out_size, void* d_ws, size_t ws_size,
                              hipStream_t stream) {
    const float* u = (const float*)d_in[0];     // f32 [64,1024,64]
    const float* W = (const float*)d_in[1];     // f32 [1024,8,32,64]
    float* out = (float*)d_out;                 // f32 [64,8,32]

    char* ws = (char*)d_ws;
    unsigned short* uh = (unsigned short*)ws;    // 33,554,432 B  u_hat bf16
    float* s0 = (float*)(ws + 33554432);         // 3 x 65,536 B contiguous
    float* s1 = s0 + B_ * EO_;
    float* s2 = s1 + B_ * EO_;
    unsigned* ctr = (unsigned*)(s2 + B_ * EO_);  // ticket counter (zeroed by k_uhat)

    k_uhat <<<dim3(N_),   dim3(256), 0, stream>>>(u, W, uh, s0, ctr);
    k_route<<<dim3(2048), dim3(256), 0, stream>>>(uh, s0, s1, s0, ctr, out, 0);
    k_route<<<dim3(2048), dim3(256), 0, stream>>>(uh, s0, s1, s1, ctr, out, 1);
    k_route<<<dim3(2048), dim3(256), 0, stream>>>(uh, s0, s1, s2, ctr, out, 2);
}

// Round 6
// 183.865 us; speedup vs baseline: 1.5544x; 1.5544x over previous
//
#include <hip/hip_runtime.h>

// EmotionCaps dynamic routing (fp32 I/O):
// u: [B=64, N=1024, I=64] f32; W: [N=1024, E=8, O=32, I=64] f32
// out: v [B=64, E=8, O=32] f32
//
// THIS ROUND: 2-dispatch structure.
//   k_uhat     : unchanged proven GEMM (1024 blocks). No s-zeroing (all
//                routing state is now block-local).
//   k_route_all: 64 blocks (one per b) x 512 thr. ALL 3 routing iterations
//                + final squash, block-local: s[b] is a private reduction
//                over n -> NO atomics, NO fences, NO cross-block sync.
//                uh[b] (512KB) re-read 3x: HBM once, then L2/L3-hot.
// Why: r5's fence disaster calibrated the budget — routes ~15-25us each,
// k_uhat ~30-40, sum ~90-110 + 4 boundaries = 134.9. Collapsing 4
// dispatches into 1 removes 3 boundaries AND 2x 33.5MB HBM re-reads.
// Session ledger: 134.9 baseline (r0/r4) | 146.4 uh2+clamp | 141.2 uh2 |
//   144.0 partial-sum | 285.8 threadfence-fold (k_route 165us, VALU 2.9% —
//   per-wave device __threadfence costs ~100+us at 2048-blk scale on 8-XCD
//   MI355X; NEVER use for handoff).
// Verified invariants reused verbatim: MFMA fragment layout; shuffle math
// (dot over o: xor 1,2,4; softmax over E: xor 8,16,32; squash o-group:
// xor 1..16); logit identity b2 = uh.(v0+v1); absmax 0.0039 (bf16-dominated,
// reorder-tolerant — r3 evidence).

#define B_  64
#define N_  1024
#define I_  64
#define E_  8
#define O_  32
#define EO_ 256
#define PAD_ 72

typedef __bf16 bf16x8 __attribute__((ext_vector_type(8)));
typedef __bf16 bf16x4v __attribute__((ext_vector_type(4)));
typedef float  f32x4  __attribute__((ext_vector_type(4)));

__device__ __forceinline__ float bf2f(unsigned int h) {
    unsigned int x = (h & 0xffffu) << 16;
    return __builtin_bit_cast(float, x);
}
__device__ __forceinline__ void cvt_store4(unsigned short* dst, float4 q) {
    bf16x4v v;
    v[0] = (__bf16)q.x; v[1] = (__bf16)q.y; v[2] = (__bf16)q.z; v[3] = (__bf16)q.w;
    *(bf16x4v*)dst = v;
}
__device__ __forceinline__ bf16x8 cvt8(const float* __restrict__ p) {
    float4 q0 = *(const float4*)p;
    float4 q1 = *(const float4*)(p + 4);
    bf16x8 a;
    a[0] = (__bf16)q0.x; a[1] = (__bf16)q0.y; a[2] = (__bf16)q0.z; a[3] = (__bf16)q0.w;
    a[4] = (__bf16)q1.x; a[5] = (__bf16)q1.y; a[6] = (__bf16)q1.z; a[7] = (__bf16)q1.w;
    return a;
}

// ---------------------------------------------------------------------------
// K1: one block per n. D[64b x 256eo] = u[:,n,:] . W[n]^T via 16x16x32 bf16
// MFMA (fragment layouts verified rounds 3-7). u staged in LDS (A-frags);
// W frags streamed from global; D transposed through the SAME LDS buffer
// (union: 33792 B -> 4 blocks/CU) for coalesced uint2 stores.
// Pure GEMM: no zeroing, no counters (downstream is block-local).
// ---------------------------------------------------------------------------
__global__ __launch_bounds__(256) void k_uhat(const float* __restrict__ u,
                                              const float* __restrict__ W,
                                              unsigned short* __restrict__ uh) {
    const int n = blockIdx.x;
    const int t = threadIdx.x;
    const int w = t >> 6, l = t & 63;
    const int m16 = l & 15, g = l >> 4;

    __shared__ __align__(16) unsigned short sh[B_ * 264];   // 33792 B (union)
    unsigned short* ul = sh;        // phase 1: u tile [B_][PAD_]
    unsigned short* Dt = sh;        // phase 2: D tile [B_][264]

#pragma unroll
    for (int j = 0; j < 4; ++j) {
        int idx = j * 256 + t;
        int b = idx >> 4, c = idx & 15;
        float4 q = *(const float4*)(u + (size_t)b * (N_ * I_) + n * I_ + c * 4);
        cvt_store4(&ul[b * PAD_ + c * 4], q);
    }
    __syncthreads();

    bf16x8 afr[4][2];   // A[m=lane&15][k=(lane>>4)*8+j]
#pragma unroll
    for (int mt = 0; mt < 4; ++mt)
#pragma unroll
        for (int ks = 0; ks < 2; ++ks)
            afr[mt][ks] = *(const bf16x8*)&ul[(mt * 16 + m16) * PAD_ + ks * 32 + g * 8];
    __syncthreads();    // all waves done reading ul; sh now reusable as Dt

    f32x4 acc[4][4];
#pragma unroll
    for (int nt = 0; nt < 4; ++nt)
#pragma unroll
        for (int mt = 0; mt < 4; ++mt)
            acc[nt][mt] = (f32x4){0.f, 0.f, 0.f, 0.f};

    const float* Wn = W + (size_t)n * (EO_ * I_);
#pragma unroll
    for (int nt = 0; nt < 4; ++nt) {
        const int eo = w * 64 + nt * 16 + m16;
        const float* wp = Wn + (size_t)eo * I_ + g * 8;
        bf16x8 b0 = cvt8(wp);
        bf16x8 b1 = cvt8(wp + 32);
#pragma unroll
        for (int mt = 0; mt < 4; ++mt) {
            acc[nt][mt] = __builtin_amdgcn_mfma_f32_16x16x32_bf16(afr[mt][0], b0, acc[nt][mt], 0, 0, 0);
            acc[nt][mt] = __builtin_amdgcn_mfma_f32_16x16x32_bf16(afr[mt][1], b1, acc[nt][mt], 0, 0, 0);
        }
    }

    // D lane map: col=lane&15, row=(lane>>4)*4+reg -> LDS transpose (hw cvt)
#pragma unroll
    for (int nt = 0; nt < 4; ++nt) {
        const int col = w * 64 + nt * 16 + m16;
#pragma unroll
        for (int mt = 0; mt < 4; ++mt)
#pragma unroll
            for (int r = 0; r < 4; ++r) {
                __bf16 hv = (__bf16)acc[nt][mt][r];
                Dt[(mt * 16 + g * 4 + r) * 264 + col] =
                    __builtin_bit_cast(unsigned short, hv);
            }
    }
    __syncthreads();
#pragma unroll
    for (int r = 0; r < 16; ++r) {
        const int row = r * 4 + w;
        uint2 q = *(const uint2*)&Dt[row * 264 + l * 4];
        *(uint2*)(uh + (size_t)row * (N_ * EO_) + (size_t)n * EO_ + l * 4) = q;
    }
}

// ---------------------------------------------------------------------------
// K2: ALL routing. One block per b (64 blocks x 512 thr = 8 waves).
// Per iteration: 16 passes x (8 waves x 8 n) covers N=1024; lane l owns
// eo = 4l..4l+3 (e = l>>3) — shuffle math verbatim from the proven k_route.
// s-reduce: LDS red[8][256]; v via k_out-style o-group shuffle (thr 0-255);
// vcur[256] carries v0 (it1) then v0+v1 (it2). it2 writes out = squash(s2).
// Block-local everything: no atomics, no fences, no races.
// ---------------------------------------------------------------------------
__global__ __launch_bounds__(512) void k_route_all(const unsigned short* __restrict__ uh,
                                                   float* __restrict__ out) {
    const int b = blockIdx.x;
    const int t = threadIdx.x;
    const int wave = t >> 6, l = t & 63;

    const unsigned short* ub = uh + (size_t)b * (N_ * EO_) + 4 * l;

    __shared__ __align__(16) float red[8][EO_];    // 8 KB
    __shared__ __align__(16) float vcur[EO_];      // v0, then v0+v1

    for (int it = 0; it < 3; ++it) {
        float4 vv;
        if (it != 0) vv = *(const float4*)&vcur[4 * l];

        float a0 = 0.f, a1 = 0.f, a2 = 0.f, a3 = 0.f;

        for (int pass = 0; pass < 16; ++pass) {
            const unsigned short* base = ub + (size_t)(pass * 64 + wave * 8) * EO_;
            float x[8][4];
            float c[8];
#pragma unroll
            for (int nn = 0; nn < 8; ++nn) {
                uint2 p = *(const uint2*)(base + nn * EO_);
                x[nn][0] = bf2f(p.x); x[nn][1] = bf2f(p.x >> 16);
                x[nn][2] = bf2f(p.y); x[nn][3] = bf2f(p.y >> 16);
            }
            if (it == 0) {
#pragma unroll
                for (int nn = 0; nn < 8; ++nn) c[nn] = 0.125f;
            } else {
                float lg[8];
#pragma unroll
                for (int nn = 0; nn < 8; ++nn) {
                    float pd = x[nn][0] * vv.x + x[nn][1] * vv.y
                             + x[nn][2] * vv.z + x[nn][3] * vv.w;
                    pd += __shfl_xor(pd, 1);
                    pd += __shfl_xor(pd, 2);
                    pd += __shfl_xor(pd, 4);      // logit(n,e) in all 8 e-lanes
                    lg[nn] = pd;
                }
                float mx[8];
#pragma unroll
                for (int nn = 0; nn < 8; ++nn) mx[nn] = lg[nn];
#pragma unroll
                for (int nn = 0; nn < 8; ++nn) mx[nn] = fmaxf(mx[nn], __shfl_xor(mx[nn], 8));
#pragma unroll
                for (int nn = 0; nn < 8; ++nn) mx[nn] = fmaxf(mx[nn], __shfl_xor(mx[nn], 16));
#pragma unroll
                for (int nn = 0; nn < 8; ++nn) mx[nn] = fmaxf(mx[nn], __shfl_xor(mx[nn], 32));
                float ex[8], sm[8];
#pragma unroll
                for (int nn = 0; nn < 8; ++nn) { ex[nn] = __expf(lg[nn] - mx[nn]); sm[nn] = ex[nn]; }
#pragma unroll
                for (int nn = 0; nn < 8; ++nn) sm[nn] += __shfl_xor(sm[nn], 8);
#pragma unroll
                for (int nn = 0; nn < 8; ++nn) sm[nn] += __shfl_xor(sm[nn], 16);
#pragma unroll
                for (int nn = 0; nn < 8; ++nn) sm[nn] += __shfl_xor(sm[nn], 32);
#pragma unroll
                for (int nn = 0; nn < 8; ++nn) c[nn] = ex[nn] * __builtin_amdgcn_rcpf(sm[nn]);
            }
#pragma unroll
            for (int nn = 0; nn < 8; ++nn) {
                a0 = fmaf(c[nn], x[nn][0], a0); a1 = fmaf(c[nn], x[nn][1], a1);
                a2 = fmaf(c[nn], x[nn][2], a2); a3 = fmaf(c[nn], x[nn][3], a3);
            }
        }

        *(float4*)&red[wave][4 * l] = make_float4(a0, a1, a2, a3);
        __syncthreads();

        if (t < EO_) {
            // s[b][t] = sum over 8 wave rows; then k_out-style squash:
            // t = eo; o-group = 32 consecutive lanes (xor 1..16 stays inside).
            float sv = ((red[0][t] + red[1][t]) + (red[2][t] + red[3][t]))
                     + ((red[4][t] + red[5][t]) + (red[6][t] + red[7][t]));
            float sq = sv * sv;
            sq += __shfl_xor(sq, 1);
            sq += __shfl_xor(sq, 2);
            sq += __shfl_xor(sq, 4);
            sq += __shfl_xor(sq, 8);
            sq += __shfl_xor(sq, 16);
            float nrm = sqrtf(sq);
            float vt = sq / ((1.f + sq) * (nrm + 1e-8f)) * sv;
            if (it == 0)      vcur[t] = vt;            // v0
            else if (it == 1) vcur[t] = vcur[t] + vt;  // v0 + v1
            else              out[b * EO_ + t] = vt;   // final squash(s2)
        }
        __syncthreads();
    }
}

extern "C" void kernel_launch(void* const* d_in, const int* in_sizes, int n_in,
                              void* d_out, int out_size, void* d_ws, size_t ws_size,
                              hipStream_t stream) {
    const float* u = (const float*)d_in[0];     // f32 [64,1024,64]
    const float* W = (const float*)d_in[1];     // f32 [1024,8,32,64]
    float* out = (float*)d_out;                 // f32 [64,8,32]

    unsigned short* uh = (unsigned short*)d_ws;  // 33,554,432 B  u_hat bf16

    k_uhat     <<<dim3(N_), dim3(256), 0, stream>>>(u, W, uh);
    k_route_all<<<dim3(B_), dim3(512), 0, stream>>>(uh, out);
}

// Round 7
// 139.171 us; speedup vs baseline: 2.0536x; 1.3211x over previous
//
#include <hip/hip_runtime.h>

// EmotionCaps dynamic routing (fp32 I/O):
// u: [B=64, N=1024, I=64] f32; W: [N=1024, E=8, O=32, I=64] f32
// out: v [B=64, E=8, O=32] f32
//
// Structure (5 dispatches — kernel boundaries are the only cross-block sync):
//   k_uhat   : u_hat bf16 (32MB ws) via 16x16x32 bf16 MFMA; zeroes s0/s1/s2.
//   k_route 0: c=1/8            -> atomicAdd s0
//   k_route 1: v0=squash(s0)    -> logits=uh.v0   -> atomicAdd s1
//   k_route 2: v01=v0+v1        -> logits=uh.v01  -> atomicAdd s2
//   k_out    : out = squash(s2)
//
// Session budget (reconciled r4/r5/r6): timed window = ~41us harness
// poison-fill (fixed tax, 256MiB fillBuffer INSIDE the window) + k_uhat
// ~40-60us + routes ~11-14us each + k_out ~2 + boundaries ~1-2us each.
// Ledger: 134.9 baseline (r0/r4) | 146.4 uh2+clamp | 141.2 uh2 |
//   144.0 partial-sum | 285.8 fence-fold (per-wave __threadfence ~100+us
//   at 2048-blk scale — NEVER) | 183.9 64-block route fusion (OCC 5.3%,
//   75% of CUs idle — b-only parallelism is structurally dead; boundaries
//   are cheap ~1-2us, fusion is low-ROI).
//
// THIS ROUND (single variable: k_uhat only; routes/k_out byte-identical r4):
// 512-thread k_uhat. (a) 8 waves x 32eo -> acc halves to 32 VGPR, est ~110
// live < 128 -> guaranteed 4 waves/SIMD, 2 blocks/CU, exactly 2 grid rounds
// (old: ~130 VGPR -> 3 blk/CU -> 1.33 rounds + straggler at 1/3 device).
// (b) W prefetch: both nt tiles' raw float4s issued upfront (one HBM
// latency window), cvt after. Same per-tile MFMA math/K-order -> uh
// bit-identical -> absmax unchanged.
// Decision: <=127 k_uhat confirmed+continue | 133-137 exonerated -> routes
// (fp8 uh) | >=140 revert.

#define B_  64
#define N_  1024
#define I_  64
#define E_  8
#define O_  32
#define EO_ 256
#define PAD_ 72

typedef __bf16 bf16x8 __attribute__((ext_vector_type(8)));
typedef __bf16 bf16x4v __attribute__((ext_vector_type(4)));
typedef float  f32x4  __attribute__((ext_vector_type(4)));

__device__ __forceinline__ float bf2f(unsigned int h) {
    unsigned int x = (h & 0xffffu) << 16;
    return __builtin_bit_cast(float, x);
}
__device__ __forceinline__ void cvt_store4(unsigned short* dst, float4 q) {
    bf16x4v v;
    v[0] = (__bf16)q.x; v[1] = (__bf16)q.y; v[2] = (__bf16)q.z; v[3] = (__bf16)q.w;
    *(bf16x4v*)dst = v;
}
__device__ __forceinline__ bf16x8 pack8(float4 q0, float4 q1) {
    bf16x8 a;
    a[0] = (__bf16)q0.x; a[1] = (__bf16)q0.y; a[2] = (__bf16)q0.z; a[3] = (__bf16)q0.w;
    a[4] = (__bf16)q1.x; a[5] = (__bf16)q1.y; a[6] = (__bf16)q1.z; a[7] = (__bf16)q1.w;
    return a;
}
// squash over the 32-elem o-group; lane l holds s[4l..4l+3] of its e-group
// (8 lanes x 4). shfl 1,2,4 stays inside the 8-lane e-group.
__device__ __forceinline__ float4 squash4(float4 s4) {
    float sq = s4.x * s4.x + s4.y * s4.y + s4.z * s4.z + s4.w * s4.w;
    sq += __shfl_xor(sq, 1);
    sq += __shfl_xor(sq, 2);
    sq += __shfl_xor(sq, 4);
    float nrm = sqrtf(sq);
    float sc = sq / ((1.f + sq) * (nrm + 1e-8f));
    return make_float4(sc * s4.x, sc * s4.y, sc * s4.z, sc * s4.w);
}

// ---------------------------------------------------------------------------
// K1: one block per n, 512 threads = 8 waves; wave w owns eo in
// [w*32, w*32+32) (2 tiles of 16). D[64b x 256eo] = u[:,n,:] . W[n]^T via
// 16x16x32 bf16 MFMA (fragment layouts verified rounds 3-7; per-tile math
// identical to the 256-thr version, only wave->tile assignment changed).
// u staged in LDS (A-frags); W raw-prefetched (both nt upfront) then cvt;
// D transposed through the SAME LDS union for coalesced uint2 stores.
// ~110 est VGPR -> 4 waves/SIMD, 2 blocks/CU, grid = exactly 2 rounds.
// Blocks 0..2 zero s0/s1/s2 (workspace is poisoned each call).
// ---------------------------------------------------------------------------
__global__ __launch_bounds__(512) void k_uhat(const float* __restrict__ u,
                                              const float* __restrict__ W,
                                              unsigned short* __restrict__ uh,
                                              float* __restrict__ s012) {
    const int n = blockIdx.x;
    const int t = threadIdx.x;
    const int w = t >> 6, l = t & 63;          // w 0..7
    const int m16 = l & 15, g = l >> 4;

    if (n < 3) {
        float* sz = s012 + n * (B_ * EO_);
#pragma unroll
        for (int i = 0; i < 32; ++i) sz[i * 512 + t] = 0.f;
    }

    __shared__ __align__(16) unsigned short sh[B_ * 264];   // 33792 B (union)
    unsigned short* ul = sh;        // phase 1: u tile [B_][PAD_]
    unsigned short* Dt = sh;        // phase 2: D tile [B_][264]

#pragma unroll
    for (int j = 0; j < 2; ++j) {
        int idx = j * 512 + t;
        int b = idx >> 4, c = idx & 15;
        float4 q = *(const float4*)(u + (size_t)b * (N_ * I_) + n * I_ + c * 4);
        cvt_store4(&ul[b * PAD_ + c * 4], q);
    }
    __syncthreads();

    bf16x8 afr[4][2];   // A[m=lane&15][k=(lane>>4)*8+j]  (all 4 b-tiles)
#pragma unroll
    for (int mt = 0; mt < 4; ++mt)
#pragma unroll
        for (int ks = 0; ks < 2; ++ks)
            afr[mt][ks] = *(const bf16x8*)&ul[(mt * 16 + m16) * PAD_ + ks * 32 + g * 8];
    __syncthreads();    // all waves done reading ul; sh now reusable as Dt

    f32x4 acc[2][4];
#pragma unroll
    for (int nt = 0; nt < 2; ++nt)
#pragma unroll
        for (int mt = 0; mt < 4; ++mt)
            acc[nt][mt] = (f32x4){0.f, 0.f, 0.f, 0.f};

    // W prefetch: both eo-tiles' raw rows in flight before any cvt/MFMA
    const float* Wn = W + (size_t)n * (EO_ * I_);
    float4 raw[2][4];
#pragma unroll
    for (int nt = 0; nt < 2; ++nt) {
        const int eo = w * 32 + nt * 16 + m16;
        const float* wp = Wn + (size_t)eo * I_ + g * 8;
        raw[nt][0] = *(const float4*)wp;
        raw[nt][1] = *(const float4*)(wp + 4);
        raw[nt][2] = *(const float4*)(wp + 32);
        raw[nt][3] = *(const float4*)(wp + 36);
    }
#pragma unroll
    for (int nt = 0; nt < 2; ++nt) {
        bf16x8 b0 = pack8(raw[nt][0], raw[nt][1]);   // K 0..31 slice (g*8+j)
        bf16x8 b1 = pack8(raw[nt][2], raw[nt][3]);   // K 32..63 slice
#pragma unroll
        for (int mt = 0; mt < 4; ++mt) {
            acc[nt][mt] = __builtin_amdgcn_mfma_f32_16x16x32_bf16(afr[mt][0], b0, acc[nt][mt], 0, 0, 0);
            acc[nt][mt] = __builtin_amdgcn_mfma_f32_16x16x32_bf16(afr[mt][1], b1, acc[nt][mt], 0, 0, 0);
        }
    }

    // D lane map: col=lane&15, row=(lane>>4)*4+reg -> LDS transpose (hw cvt)
#pragma unroll
    for (int nt = 0; nt < 2; ++nt) {
        const int col = w * 32 + nt * 16 + m16;
#pragma unroll
        for (int mt = 0; mt < 4; ++mt)
#pragma unroll
            for (int r = 0; r < 4; ++r) {
                __bf16 hv = (__bf16)acc[nt][mt][r];
                Dt[(mt * 16 + g * 4 + r) * 264 + col] =
                    __builtin_bit_cast(unsigned short, hv);
            }
    }
    __syncthreads();
#pragma unroll
    for (int r = 0; r < 8; ++r) {
        const int row = r * 8 + w;
        uint2 q = *(const uint2*)&Dt[row * 264 + l * 4];
        *(uint2*)(uh + (size_t)row * (N_ * EO_) + (size_t)n * EO_ + l * 4) = q;
    }
}

// ---------------------------------------------------------------------------
// K2: one routing pass. 2048 blocks = (b, chunk of 32 n); wave handles 8 n;
// lane l owns eo = 4l..4l+3 (e = l>>3). Shuffle math verified rounds 2-7:
// dot over o = shfl 1,2,4; softmax over E = shfl 8,16,32.
// it selects the v recomputation (from s0/s1, visible since prior dispatch
// completed) and the target accumulator. One atomicAdd per (b,eo) per block.
// BYTE-IDENTICAL to the proven r4 baseline.
// ---------------------------------------------------------------------------
__global__ __launch_bounds__(256) void k_route(const unsigned short* __restrict__ uh,
                                               const float* __restrict__ s0,
                                               const float* __restrict__ s1,
                                               float* __restrict__ tgt,
                                               int it) {
    const int blk = blockIdx.x;
    const int b = blk >> 5, chunk = blk & 31;
    const int t = threadIdx.x, wave = t >> 6, l = t & 63;

    const unsigned short* base = uh + (size_t)b * (N_ * EO_)
                                    + (size_t)(chunk * 32 + wave * 8) * EO_ + 4 * l;
    float x[8][4];
    float c[8];

    if (it == 0) {
#pragma unroll
        for (int nn = 0; nn < 8; ++nn) {
            uint2 p = *(const uint2*)(base + nn * EO_);
            x[nn][0] = bf2f(p.x); x[nn][1] = bf2f(p.x >> 16);
            x[nn][2] = bf2f(p.y); x[nn][3] = bf2f(p.y >> 16);
            c[nn] = 0.125f;
        }
    } else {
        // recompute v (and v0+v1 for it==2) from s-buffers: ~20 VALU, L2-hot
        float4 v4 = squash4(*(const float4*)(s0 + b * EO_ + 4 * l));
        if (it == 2) {
            float4 v1 = squash4(*(const float4*)(s1 + b * EO_ + 4 * l));
            v4.x += v1.x; v4.y += v1.y; v4.z += v1.z; v4.w += v1.w;
        }
        float lg[8];
#pragma unroll
        for (int nn = 0; nn < 8; ++nn) {
            uint2 p = *(const uint2*)(base + nn * EO_);
            x[nn][0] = bf2f(p.x); x[nn][1] = bf2f(p.x >> 16);
            x[nn][2] = bf2f(p.y); x[nn][3] = bf2f(p.y >> 16);
            float pd = x[nn][0] * v4.x + x[nn][1] * v4.y
                     + x[nn][2] * v4.z + x[nn][3] * v4.w;
            pd += __shfl_xor(pd, 1);
            pd += __shfl_xor(pd, 2);
            pd += __shfl_xor(pd, 4);              // logit(n,e) in all 8 e-lanes
            lg[nn] = pd;
        }
        float mx[8];
#pragma unroll
        for (int nn = 0; nn < 8; ++nn) mx[nn] = lg[nn];
#pragma unroll
        for (int nn = 0; nn < 8; ++nn) mx[nn] = fmaxf(mx[nn], __shfl_xor(mx[nn], 8));
#pragma unroll
        for (int nn = 0; nn < 8; ++nn) mx[nn] = fmaxf(mx[nn], __shfl_xor(mx[nn], 16));
#pragma unroll
        for (int nn = 0; nn < 8; ++nn) mx[nn] = fmaxf(mx[nn], __shfl_xor(mx[nn], 32));
        float ex[8], sm[8];
#pragma unroll
        for (int nn = 0; nn < 8; ++nn) { ex[nn] = __expf(lg[nn] - mx[nn]); sm[nn] = ex[nn]; }
#pragma unroll
        for (int nn = 0; nn < 8; ++nn) sm[nn] += __shfl_xor(sm[nn], 8);
#pragma unroll
        for (int nn = 0; nn < 8; ++nn) sm[nn] += __shfl_xor(sm[nn], 16);
#pragma unroll
        for (int nn = 0; nn < 8; ++nn) sm[nn] += __shfl_xor(sm[nn], 32);
#pragma unroll
        for (int nn = 0; nn < 8; ++nn) c[nn] = ex[nn] * __builtin_amdgcn_rcpf(sm[nn]);
    }

    float a0 = 0.f, a1 = 0.f, a2 = 0.f, a3 = 0.f;
#pragma unroll
    for (int nn = 0; nn < 8; ++nn) {
        a0 = fmaf(c[nn], x[nn][0], a0); a1 = fmaf(c[nn], x[nn][1], a1);
        a2 = fmaf(c[nn], x[nn][2], a2); a3 = fmaf(c[nn], x[nn][3], a3);
    }

    __shared__ __align__(16) float red[4][EO_];
    *(float4*)&red[wave][4 * l] = make_float4(a0, a1, a2, a3);
    __syncthreads();
    atomicAdd(&tgt[b * EO_ + t], red[0][t] + red[1][t] + red[2][t] + red[3][t]);
}

// ---------------------------------------------------------------------------
// K3: out = squash(s2). 64 blocks x 256 (t = eo; o-group = 32 lanes).
// ---------------------------------------------------------------------------
__global__ __launch_bounds__(256) void k_out(const float* __restrict__ s2,
                                             float* __restrict__ out) {
    const int b = blockIdx.x, t = threadIdx.x;
    float sv = s2[b * EO_ + t];
    float sq = sv * sv;
    sq += __shfl_xor(sq, 1);
    sq += __shfl_xor(sq, 2);
    sq += __shfl_xor(sq, 4);
    sq += __shfl_xor(sq, 8);
    sq += __shfl_xor(sq, 16);
    float nrm = sqrtf(sq);
    out[b * EO_ + t] = sq / ((1.f + sq) * (nrm + 1e-8f)) * sv;
}

extern "C" void kernel_launch(void* const* d_in, const int* in_sizes, int n_in,
                              void* d_out, int out_size, void* d_ws, size_t ws_size,
                              hipStream_t stream) {
    const float* u = (const float*)d_in[0];     // f32 [64,1024,64]
    const float* W = (const float*)d_in[1];     // f32 [1024,8,32,64]
    float* out = (float*)d_out;                 // f32 [64,8,32]

    char* ws = (char*)d_ws;
    unsigned short* uh = (unsigned short*)ws;    // 33,554,432 B  u_hat bf16
    float* s0 = (float*)(ws + 33554432);         // 3 x 65,536 B contiguous
    float* s1 = s0 + B_ * EO_;
    float* s2 = s1 + B_ * EO_;

    k_uhat <<<dim3(N_),   dim3(512), 0, stream>>>(u, W, uh, s0);
    k_route<<<dim3(2048), dim3(256), 0, stream>>>(uh, s0, s1, s0, 0);
    k_route<<<dim3(2048), dim3(256), 0, stream>>>(uh, s0, s1, s1, 1);
    k_route<<<dim3(2048), dim3(256), 0, stream>>>(uh, s0, s1, s2, 2);
    k_out  <<<dim3(B_),   dim3(256), 0, stream>>>(s2, out);
}